// Round 17
// baseline (97.028 us; speedup 1.0000x reference)
//
#include <hip/hip_runtime.h>

#define NPTS    65536
#define DIM     128
#define KCODES  1024
#define BM      128      // points per argmin block (4 waves x 32 points)
#define TILE_C  64       // codes per LDS tile (double-buffered 2x16 KB)
#define NTHR    256
#define NTILE   (KCODES / TILE_C)   // 16

typedef _Float16 f16x8  __attribute__((ext_vector_type(8)));
typedef float    f32x16 __attribute__((ext_vector_type(16)));

__device__ __forceinline__ void gload_lds16(const void* g, void* l) {
    __builtin_amdgcn_global_load_lds(
        (const __attribute__((address_space(1))) void*)g,
        (__attribute__((address_space(3))) void*)l, 16, 0, 0);
}

// ---------------- Kernel P: pack codebook -> fp16 frag-order (32x32 MFMA) ------
// + halfnorm(rounded) + init acc/ghist/gcursor.
// g in 0..16383: tc=g>>10 (tile of 64 codes), f=(g>>6)&15, l=g&63.
// f = nt*8+kc (nt: 32-code group, kc: k-chunk of 16).
// code c = tc*64 + nt*32 + (l&31) ; d0 = kc*16 + (l>>5)*8.
__global__ __launch_bounds__(256)
void pack_kernel(const float* __restrict__ embed, _Float16* __restrict__ ebf,
                 int* __restrict__ ghist, int* __restrict__ gcursor,
                 const float* __restrict__ ema_embed, float* __restrict__ acc,
                 float* __restrict__ hn)
{
    __shared__ float partial[256];
    const int t = threadIdx.x;
    const int b = blockIdx.x;
    const int g = b * 256 + t;                       // 0..16383
    if (g < KCODES) { ghist[g] = 0; gcursor[g] = 0; }
    {   // init acc = 0.8 * ema_embed (2 float4s per thread = 32768 total)
        float4 e0 = reinterpret_cast<const float4*>(ema_embed)[g];
        float4 e1 = reinterpret_cast<const float4*>(ema_embed)[g + 16384];
        reinterpret_cast<float4*>(acc)[g] =
            (float4){0.8f * e0.x, 0.8f * e0.y, 0.8f * e0.z, 0.8f * e0.w};
        reinterpret_cast<float4*>(acc)[g + 16384] =
            (float4){0.8f * e1.x, 0.8f * e1.y, 0.8f * e1.z, 0.8f * e1.w};
    }

    // ---- pack one 8-element fragment slot ----
    {
        const int tc  = g >> 10;
        const int f   = (g >> 6) & 15;
        const int l   = g & 63;
        const int nt  = f >> 3;
        const int kc  = f & 7;
        const int c   = tc * TILE_C + nt * 32 + (l & 31);
        const int d0  = kc * 16 + (l >> 5) * 8;
        const float* src = embed + (long)c * DIM + d0;
        float4 v0 = *reinterpret_cast<const float4*>(src);
        float4 v1 = *reinterpret_cast<const float4*>(src + 4);
        float vv[8] = {v0.x, v0.y, v0.z, v0.w, v1.x, v1.y, v1.z, v1.w};
        f16x8 out;
        #pragma unroll
        for (int j = 0; j < 8; ++j) out[j] = (_Float16)vv[j];
        *reinterpret_cast<f16x8*>(ebf + (long)g * 8) = out;
    }

    // ---- halfnorm of ROUNDED codebook: 16 codes per block, 16 threads/code ----
    {
        const int c2    = b * 16 + (t >> 4);
        const int chunk = t & 15;
        const float* src = embed + (long)c2 * DIM + chunk * 8;
        float4 v0 = *reinterpret_cast<const float4*>(src);
        float4 v1 = *reinterpret_cast<const float4*>(src + 4);
        float vv[8] = {v0.x, v0.y, v0.z, v0.w, v1.x, v1.y, v1.z, v1.w};
        float ss = 0.f;
        #pragma unroll
        for (int j = 0; j < 8; ++j) {
            float r = (float)(_Float16)vv[j];        // fp16-rounded value
            ss += r * r;
        }
        partial[t] = ss;
        __syncthreads();
        if ((t & 15) == 0) {
            float s = 0.f;
            #pragma unroll
            for (int j = 0; j < 16; ++j) s += partial[t + j];
            hn[c2] = 0.5f * s;
        }
    }
}

// ---------------- Kernel 1: 32x32x16 fp16 MFMA argmin over FULL codebook -------
// grid 512 (BM=128, wave owns 32 points). Fused: ind + quantize + histogram.
// A: row = lane&31 (point), k = (lane>>5)*8+j per k-chunk.
// C/D: col(code) = lane&31, row(point) = (reg&3)+8*(reg>>2)+4*(lane>>5).
__global__ __launch_bounds__(NTHR, 2)
void argmin_kernel(const float* __restrict__ x, const _Float16* __restrict__ ebf,
                   const float* __restrict__ halfnorm, const float* __restrict__ embed,
                   int* __restrict__ ind, float* __restrict__ quant,
                   int* __restrict__ ghist)
{
    __shared__ _Float16 es[2][8192];    // 2 x 16 KB double-buffered tile
    __shared__ int      hist[KCODES];   // 4 KB
    __shared__ int      bidx[BM];

    const int t    = threadIdx.x;
    const int lane = t & 63;
    const int w    = t >> 6;           // wave 0..3, owns 32 points
    const int r32  = lane & 31;
    const int ksub = lane >> 5;        // k-subgroup (0/1)
    const long xbase = (long)blockIdx.x * BM * DIM;
    const int  wp    = w * 32;

    for (int i = t; i < KCODES; i += NTHR) hist[i] = 0;

    // ---- A fragments: row (wp + r32), 8 k-chunks of 16 ----
    f16x8 a[8];
    {
        const long prow = xbase + (long)(wp + r32) * DIM;
        #pragma unroll
        for (int kc = 0; kc < 8; ++kc) {
            const float* s = x + prow + kc * 16 + ksub * 8;
            float4 u0 = *reinterpret_cast<const float4*>(s);
            float4 u1 = *reinterpret_cast<const float4*>(s + 4);
            float vv[8] = {u0.x, u0.y, u0.z, u0.w, u1.x, u1.y, u1.z, u1.w};
            #pragma unroll
            for (int j = 0; j < 8; ++j) a[kc][j] = (_Float16)vv[j];
        }
    }

    // ---- prologue: stage tile 0 (wave w loads frags w*4..w*4+3, 1 KB each) ----
    #pragma unroll
    for (int i = 0; i < 4; ++i) {
        const int f = w * 4 + i;
        gload_lds16(ebf + (long)f * 512 + lane * 8, &es[0][f * 512]);
    }
    float hnv_cur[2], hnv_nxt[2];
    #pragma unroll
    for (int nt = 0; nt < 2; ++nt) hnv_cur[nt] = halfnorm[nt * 32 + r32];
    __syncthreads();   // tile 0 resident; hist zeroed

    float bestv[16];
    int   besti[16];
    #pragma unroll
    for (int s = 0; s < 16; ++s) { bestv[s] = -1e30f; besti[s] = 0; }

    #pragma unroll 1
    for (int tile = 0; tile < NTILE; ++tile) {
        // issue next tile's stage + next halfnorms (latency hides under MFMA)
        if (tile + 1 < NTILE) {
            const long gbase = (long)(tile + 1) * 8192;
            #pragma unroll
            for (int i = 0; i < 4; ++i) {
                const int f = w * 4 + i;
                gload_lds16(ebf + gbase + f * 512 + lane * 8, &es[(tile + 1) & 1][f * 512]);
            }
            #pragma unroll
            for (int nt = 0; nt < 2; ++nt)
                hnv_nxt[nt] = halfnorm[(tile + 1) * TILE_C + nt * 32 + r32];
        }

        #pragma unroll
        for (int nt = 0; nt < 2; ++nt) {
            f32x16 C = {0.f, 0.f, 0.f, 0.f, 0.f, 0.f, 0.f, 0.f,
                        0.f, 0.f, 0.f, 0.f, 0.f, 0.f, 0.f, 0.f};
            #pragma unroll
            for (int kc = 0; kc < 8; ++kc) {
                f16x8 B = *reinterpret_cast<const f16x8*>(
                    &es[tile & 1][(nt * 8 + kc) * 512 + lane * 8]);
                C = __builtin_amdgcn_mfma_f32_32x32x16_f16(a[kc], B, C, 0, 0, 0);
            }
            // scores + running argmax; lane's code col = nt*32 + r32
            const int c = tile * TILE_C + nt * 32 + r32;
            const float hnv = hnv_cur[nt];
            #pragma unroll
            for (int reg = 0; reg < 16; ++reg) {
                float sc = C[reg] - hnv;
                if (sc > bestv[reg]) { bestv[reg] = sc; besti[reg] = c; }
            }
        }
        hnv_cur[0] = hnv_nxt[0];
        hnv_cur[1] = hnv_nxt[1];
        __syncthreads();   // next tile resident; current tile readers done
    }

    // ---- butterfly reduce across 32 code-columns (xor bits 0..4) --------------
    #pragma unroll
    for (int s = 0; s < 16; ++s) {
        float v = bestv[s];
        int   i = besti[s];
        #pragma unroll
        for (int off = 1; off < 32; off <<= 1) {
            float ov = __shfl_xor(v, off);
            int   oi = __shfl_xor(i, off);
            if (ov > v || (ov == v && oi < i)) { v = ov; i = oi; }
        }
        bestv[s] = v; besti[s] = i;
    }
    if (r32 == 0) {   // lanes 0 and 32 each write 16 points
        #pragma unroll
        for (int s = 0; s < 16; ++s) {
            int p = wp + (s & 3) + 8 * (s >> 2) + 4 * ksub;
            bidx[p] = besti[s];
            ind[blockIdx.x * BM + p] = besti[s];
        }
    }
    __syncthreads();

    // ---- LDS histogram of this block's 128 assignments ----
    if (t < BM) atomicAdd(&hist[bidx[t]], 1);

    // ---- quantize: lane-contiguous gather-copy of embed[best] ----
    float4* dst = reinterpret_cast<float4*>(quant + xbase);
    #pragma unroll
    for (int i = 0; i < 16; ++i) {
        int idx = i * NTHR + t;          // 0..4095
        int p   = idx >> 5;
        int q   = idx & 31;
        int c   = bidx[p];
        dst[idx] = reinterpret_cast<const float4*>(embed + (long)c * DIM)[q];
    }

    __syncthreads();
    for (int i = t; i < KCODES; i += NTHR)
        if (hist[i]) atomicAdd(&ghist[i], hist[i]);
}

// ---------------- Kernel C: scan(ghist) in-block + scatter + ema_num_new -------
__global__ __launch_bounds__(256)
void scatter_kernel(const int* __restrict__ ghist, const int* __restrict__ ind,
                    const float* __restrict__ ema_num, float* __restrict__ ema_num_new,
                    int* __restrict__ gcursor, int* __restrict__ sorted,
                    int* __restrict__ scode)
{
    __shared__ int off_lds[KCODES];
    __shared__ int wsum[4];
    const int t    = threadIdx.x;
    const int lane = t & 63;
    const int w    = t >> 6;

    int v[4], pre[4];
    int s = 0;
    #pragma unroll
    for (int j = 0; j < 4; ++j) {
        v[j] = ghist[t * 4 + j];
        pre[j] = s;
        s += v[j];
    }
    int incl = s;
    #pragma unroll
    for (int off = 1; off < 64; off <<= 1) {
        int u = __shfl_up(incl, off);
        if (lane >= off) incl += u;
    }
    if (lane == 63) wsum[w] = incl;
    __syncthreads();
    if (t == 0) {
        int a = 0;
        #pragma unroll
        for (int k = 0; k < 4; ++k) { int tmp = wsum[k]; wsum[k] = a; a += tmp; }
    }
    __syncthreads();
    const int excl = wsum[w] + incl - s;
    #pragma unroll
    for (int j = 0; j < 4; ++j) off_lds[t * 4 + j] = excl + pre[j];

    if (blockIdx.x == 0) {
        #pragma unroll
        for (int j = 0; j < 4; ++j)
            ema_num_new[t * 4 + j] = ema_num[t * 4 + j] * 0.8f + 0.2f * (float)v[j];
    }
    __syncthreads();

    const int p = blockIdx.x * 256 + t;
    const int c = ind[p];
    const int pos = off_lds[c] + atomicAdd(&gcursor[c], 1);
    sorted[pos] = p;
    scode[pos]  = c;
}

// ---------------- Kernel G: chunked run-sum over sorted order ------------------
__global__ __launch_bounds__(128)
void sum2_kernel(const float* __restrict__ x, const int* __restrict__ sorted,
                 const int* __restrict__ scode, float* __restrict__ acc)
{
    __shared__ int sp[64];
    __shared__ int sc[64];
    const int t = threadIdx.x;
    const int base = blockIdx.x * 64;
    if (t < 64) { sp[t] = sorted[base + t]; sc[t] = scode[base + t]; }
    __syncthreads();

    float a = 0.f;
    int cprev = sc[0];
    #pragma unroll 1
    for (int kk = 0; kk < 8; ++kk) {
        float v[8];
        #pragma unroll
        for (int i = 0; i < 8; ++i)
            v[i] = x[(long)sp[kk * 8 + i] * DIM + t];      // 8 independent 512B rows
        #pragma unroll
        for (int i = 0; i < 8; ++i) {
            const int c = sc[kk * 8 + i];                  // wave-uniform
            if (c != cprev) {
                atomicAdd(&acc[(long)cprev * DIM + t], 0.2f * a);
                a = 0.f; cprev = c;
            }
            a += v[i];
        }
    }
    atomicAdd(&acc[(long)cprev * DIM + t], 0.2f * a);
}

// ---------------- Kernel F: embed_new = ema_embed_new / ema_num_new ------------
__global__ __launch_bounds__(256)
void final_kernel(const float* __restrict__ acc, const float* __restrict__ ema_num_new,
                  float* __restrict__ embed_new)
{
    const int g = blockIdx.x * 256 + threadIdx.x;   // 0..32767 float4s
    float4 v = reinterpret_cast<const float4*>(acc)[g];
    const float en = ema_num_new[g >> 5];           // 32 float4s per code row
    float4 o = {v.x / en, v.y / en, v.z / en, v.w / en};
    reinterpret_cast<float4*>(embed_new)[g] = o;
}

extern "C" void kernel_launch(void* const* d_in, const int* in_sizes, int n_in,
                              void* d_out, int out_size, void* d_ws, size_t ws_size,
                              hipStream_t stream)
{
    const float* x         = (const float*)d_in[0];
    const float* embed     = (const float*)d_in[1];
    const float* ema_embed = (const float*)d_in[2];
    const float* ema_num   = (const float*)d_in[3];

    float* out0 = (float*)d_out;            // quantize      (16*4096*128)
    float* out1 = out0 + 8388608;           // embed_new     (1024*128)
    float* out2 = out1 + 131072;            // ema_embed_new (1024*128)
    float* out3 = out2 + 131072;            // ema_num_new   (1024)

    char* ws = (char*)d_ws;
    float*    hn      = (float*)ws;                 // 4 KB
    int*      ind     = (int*)(ws + 4096);          // 256 KB
    _Float16* ebf     = (_Float16*)(ws + 266240);   // 256 KB
    int*      ghist   = (int*)(ws + 528384);        // 4 KB
    int*      gcursor = (int*)(ws + 532480);        // 4 KB
    int*      sorted  = (int*)(ws + 536576);        // 256 KB
    int*      scode   = (int*)(ws + 798720);        // 256 KB

    pack_kernel<<<64, 256, 0, stream>>>(embed, ebf, ghist, gcursor, ema_embed,
                                        out2, hn);
    argmin_kernel<<<NPTS / BM, NTHR, 0, stream>>>(x, ebf, hn, embed, ind, out0, ghist);
    scatter_kernel<<<NPTS / 256, 256, 0, stream>>>(ghist, ind, ema_num, out3,
                                                   gcursor, sorted, scode);
    sum2_kernel<<<NPTS / 64, 128, 0, stream>>>(x, sorted, scode, out2);
    final_kernel<<<128, 256, 0, stream>>>(out2, out3, out1);
}